// Round 6
// baseline (472.286 us; speedup 1.0000x reference)
//
#include <hip/hip_runtime.h>

typedef unsigned int uint;
typedef unsigned short ushort;

#define NN 1000000
#define KSZ 9
#define CH 16
#define KTOT 144          // KSZ*CH
#define NBLK 1024         // = exact co-residency capacity at 4 blocks/CU
#define TILES64 15625     // NN / 64
#define MAXT 16           // ceil(TILES64 / NBLK) tiles per block
#define WSHIFT 19         // window = idx >> 19: 2 windows x 524288 nodes x 32B = 16MB
#define NWIN 2

typedef float f32x4 __attribute__((ext_vector_type(4)));
typedef short s16x8 __attribute__((ext_vector_type(8)));

__device__ __forceinline__ float bf2f(ushort v) { return __uint_as_float(((uint)v) << 16); }
__device__ __forceinline__ ushort f2bf(float f) {
  uint u = __float_as_uint(f);
  return (ushort)((u + 0x7fffu + ((u >> 16) & 1u)) >> 16);   // RNE
}
__device__ __forceinline__ float leaky(float x) { return x >= 0.f ? x : 0.2f * x; }

// data fp32 -> bf16 copy (conv1 rounds to bf16 for MFMA anyway; bit-identical).
// Block 0 also zeroes the two stat accumulators (absorbs the memset dispatch).
__global__ __launch_bounds__(256)
void k_cast(const float* __restrict__ in, ushort* __restrict__ out,
            float* __restrict__ accums) {
  if (blockIdx.x == 0 && threadIdx.x < 64) accums[threadIdx.x] = 0.f;
  size_t i0 = ((size_t)blockIdx.x * 256 + (size_t)threadIdx.x) * 8;
  if (i0 >= (size_t)NN * CH) return;
  float4 a = *(const float4*)(in + i0);
  float4 b = *(const float4*)(in + i0 + 4);
  float e[8] = {a.x, a.y, a.z, a.w, b.x, b.y, b.z, b.w};
  uint pk[4];
#pragma unroll
  for (int p = 0; p < 4; ++p)
    pk[p] = (uint)f2bf(e[2*p]) | ((uint)f2bf(e[2*p+1]) << 16);
  *(uint4*)(out + i0) = *(uint4*)pk;
}

// ---------------------------------------------------------------------------
// 2-window gather-conv, barrier-free. Facts from R1/R3/R4/R5: gather time =
// FETCH/3.3TB/s (concurrency-insensitive); bf16 source refetch factor 1.86
// (512MB vs 292MB per-XCD compulsory) IS reducible by temporal windowing
// (R3: FETCH 512->143 with 8 windows), but R3's device-atomic spin barrier
// was a contention catastrophe. Here: NO barrier — grid = exact co-residency
// capacity, blocks start together and per-window work is uniform (CLT:
// 180+-13 rows/wave/window), so natural drift << one window phase. NWIN=2
// keeps the revisit tax small (2x tile sweep, 2x MFMA issue ~ +10us).
// Window pass wp loads only rows with idx>>19==wp (predicated, zero-tied);
// MFMA accumulates across passes (windows partition K exactly; fp32 add
// reassociation only). BN=true (conv2): BN1+leaky applied in-register to
// LOADED lanes only (xf(0) != 0, so the select is required for correctness).
// ---------------------------------------------------------------------------
template<bool BN>
__global__ __launch_bounds__(256, 4)
void k_conv(const ushort* __restrict__ src, const int* __restrict__ ind,
            const float* __restrict__ w, const float* __restrict__ bias,
            const float* __restrict__ statsIn, const float* __restrict__ gamma,
            const float* __restrict__ beta,
            ushort* __restrict__ outv, float* __restrict__ accumOut) {
  const int lane = threadIdx.x & 63;
  const int wid  = threadIdx.x >> 6;
  const int o = lane & 15;     // node-within-tile for A rows; out channel for B/D
  const int q = lane >> 4;
  const int qh = q >> 1;
  const int ch0 = (q & 1) * 8; // 8-channel half of the 32B row this lane loads
  const int o9 = o * KSZ;

  __shared__ int   idxs[4][MAXT][KTOT];   // 36,864B: all tiles' indices, staged once
  __shared__ float red[4][32];
  __shared__ float dsc[16], dsh[16];

  // B fragments: B[k][o] = w[c*144 + o*9 + j], k = j*16 + c; lane holds k = 32t + 8q + i
  // k >= 144 (K-pad) is zero in B, so pad-lane A content is don't-care (finite).
  s16x8 bfrag[5];
#pragma unroll
  for (int t = 0; t < 5; ++t) {
#pragma unroll
    for (int i = 0; i < 8; ++i) {
      int k = t * 32 + q * 8 + i;
      ushort wv = 0;
      if (k < KTOT) { int j = k >> 4, c = k & 15; wv = f2bf(w[(c * CH + o) * KSZ + j]); }
      bfrag[t][i] = (short)wv;
    }
  }

  float bo = 0.f;
  float sc8[8], sh8[8];
  if constexpr (BN) {
    // derive BN1 scale/shift per block from the atomic accumulator
    if (threadIdx.x < 16) {
      int c = threadIdx.x;
      float s = statsIn[c], sq = statsIn[16 + c];
      float mean = s * (1.0f / NN);
      float var  = sq * (1.0f / NN) - mean * mean;
      float scale = gamma[c] * rsqrtf(var + 1e-5f);
      dsc[c] = scale; dsh[c] = beta[c] - mean * scale;
    }
    __syncthreads();
#pragma unroll
    for (int i = 0; i < 8; ++i) { sc8[i] = dsc[ch0 + i]; sh8[i] = dsh[ch0 + i]; }
  } else {
    bo = bias[o];
  }

  const int NT = (TILES64 - 1 - blockIdx.x) / NBLK + 1;   // 15 or 16 tiles

  // stage ALL tiles' indices into wave-private LDS (ind read exactly once)
#pragma unroll
  for (int tt = 0; tt < MAXT; ++tt) {
    if (tt < NT) {
      int base9 = ((blockIdx.x + tt * NBLK) * 64 + wid * 16) * 9;
      idxs[wid][tt][lane]      = ind[base9 + lane];
      idxs[wid][tt][lane + 64] = ind[base9 + lane + 64];
      if (lane < KTOT - 128) idxs[wid][tt][lane + 128] = ind[base9 + lane + 128];
    }
  }

  f32x4 acc[MAXT];
#pragma unroll
  for (int tt = 0; tt < MAXT; ++tt) acc[tt] = (f32x4){0.f, 0.f, 0.f, 0.f};

  for (int wp = 0; wp < NWIN; ++wp) {
#pragma unroll
    for (int tt = 0; tt < MAXT; ++tt) {
      if (tt >= NT) continue;              // uniform branch
      const int* tix = &idxs[wid][tt][0];
      // slot s covers k=32s..32s+31 -> neighbor j = 2s+qh (s<4), j=8 (s=4, q<2)
      int i0 = tix[o9 + 0 + qh];
      int i1 = tix[o9 + 2 + qh];
      int i2 = tix[o9 + 4 + qh];
      int i3 = tix[o9 + 6 + qh];
      int i4 = tix[o9 + 8];
      const bool w0 = (i0 >> WSHIFT) == wp;
      const bool w1 = (i1 >> WSHIFT) == wp;
      const bool w2 = (i2 >> WSHIFT) == wp;
      const bool w3 = (i3 >> WSHIFT) == wp;
      const bool w4 = (i4 >> WSHIFT) == wp;
      const ushort* p0 = src + (size_t)i0 * CH + ch0;
      const ushort* p1 = src + (size_t)i1 * CH + ch0;
      const ushort* p2 = src + (size_t)i2 * CH + ch0;
      const ushort* p3 = src + (size_t)i3 * CH + ch0;
      const ushort* p4 = src + (size_t)i4 * CH + ch0;
      s16x8 z = {0,0,0,0,0,0,0,0};
      s16x8 t0 = z, t1 = z, t2 = z, t3 = z, t4 = z;
      // predicated loads: only window-wp rows; inactive lanes keep zeros ("+v" ties init)
      if (w0) asm volatile("global_load_dwordx4 %0, %1, off sc0" : "+v"(t0) : "v"(p0) : "memory");
      if (w1) asm volatile("global_load_dwordx4 %0, %1, off sc0" : "+v"(t1) : "v"(p1) : "memory");
      if (w2) asm volatile("global_load_dwordx4 %0, %1, off sc0" : "+v"(t2) : "v"(p2) : "memory");
      if (w3) asm volatile("global_load_dwordx4 %0, %1, off sc0" : "+v"(t3) : "v"(p3) : "memory");
      if (qh == 0 && w4)   // k-pad lanes (q>=2) never load slot 4
        asm volatile("global_load_dwordx4 %0, %1, off sc0" : "+v"(t4) : "v"(p4) : "memory");
      asm volatile("s_waitcnt vmcnt(0)" ::: "memory");
      __builtin_amdgcn_sched_barrier(0);   // rule 18: keep consumers below the wait
      s16x8 a0, a1, a2, a3, a4;
      if constexpr (BN) {
        // h = leaky(scale1*x + shift1) -> bf16, ONLY on loaded lanes (xf(0) != 0)
        auto xf = [&](s16x8 v) -> s16x8 {
          s16x8 r;
#pragma unroll
          for (int i = 0; i < 8; ++i) {
            float x = bf2f((ushort)v[i]);
            r[i] = (short)f2bf(leaky(sc8[i] * x + sh8[i]));
          }
          return r;
        };
        a0 = w0 ? xf(t0) : z;
        a1 = w1 ? xf(t1) : z;
        a2 = w2 ? xf(t2) : z;
        a3 = w3 ? xf(t3) : z;
        a4 = w4 ? xf(t4) : z;
      } else {
        a0 = t0; a1 = t1; a2 = t2; a3 = t3; a4 = t4;
      }
      if (qh) a4 = z;                      // K-pad lanes (k>=144; B is zero there anyway)
      acc[tt] = __builtin_amdgcn_mfma_f32_16x16x32_bf16(a0, bfrag[0], acc[tt], 0, 0, 0);
      acc[tt] = __builtin_amdgcn_mfma_f32_16x16x32_bf16(a1, bfrag[1], acc[tt], 0, 0, 0);
      acc[tt] = __builtin_amdgcn_mfma_f32_16x16x32_bf16(a2, bfrag[2], acc[tt], 0, 0, 0);
      acc[tt] = __builtin_amdgcn_mfma_f32_16x16x32_bf16(a3, bfrag[3], acc[tt], 0, 0, 0);
      acc[tt] = __builtin_amdgcn_mfma_f32_16x16x32_bf16(a4, bfrag[4], acc[tt], 0, 0, 0);
    }
  }

  // epilogue: bias, round, store, stats on the ROUNDED values
  float wsum = 0.f, wsq = 0.f;
#pragma unroll
  for (int tt = 0; tt < MAXT; ++tt) {
    if (tt >= NT) continue;
    int base = (blockIdx.x + tt * NBLK) * 64 + wid * 16;
#pragma unroll
    for (int r = 0; r < 4; ++r) {
      float v = acc[tt][r] + bo;
      ushort hv = f2bf(v);
      outv[(size_t)(base + q * 4 + r) * CH + o] = hv;
      float vr = bf2f(hv);
      wsum += vr;
      wsq  += vr * vr;
    }
  }

  // per-channel reduce: lanes o, o+16, o+32, o+48 -> block -> global atomic
  wsum += __shfl_xor(wsum, 16);  wsum += __shfl_xor(wsum, 32);
  wsq  += __shfl_xor(wsq, 16);   wsq  += __shfl_xor(wsq, 32);
  if (lane < 16) { red[wid][lane] = wsum; red[wid][16 + lane] = wsq; }
  __syncthreads();
  if (threadIdx.x < 32) {
    float s = red[0][threadIdx.x] + red[1][threadIdx.x] + red[2][threadIdx.x] + red[3][threadIdx.x];
    atomicAdd(&accumOut[threadIdx.x], s);   // [0..15]=sum, [16..31]=sumsq
  }
}

// out = leaky(scale2*out2 + shift2 + data), fp32; BN2 derived per block
__global__ __launch_bounds__(256)
void k_final(const ushort* __restrict__ o2, const float* __restrict__ data,
             const float* __restrict__ statsIn, const float* __restrict__ gamma,
             const float* __restrict__ beta, float* __restrict__ out) {
  __shared__ float dsc[16], dsh[16];
  if (threadIdx.x < 16) {
    int c = threadIdx.x;
    float s = statsIn[c], sq = statsIn[16 + c];
    float mean = s * (1.0f / NN);
    float var  = sq * (1.0f / NN) - mean * mean;
    float scale = gamma[c] * rsqrtf(var + 1e-5f);
    dsc[c] = scale; dsh[c] = beta[c] - mean * scale;
  }
  __syncthreads();
  size_t t = (size_t)blockIdx.x * 256 + threadIdx.x;
  size_t i0 = t * 8;
  if (i0 >= (size_t)NN * CH) return;
  int coff = (int)(i0 & 15);
  float sc[8], sh[8];
#pragma unroll
  for (int p = 0; p < 8; ++p) { sc[p] = dsc[coff + p]; sh[p] = dsh[coff + p]; }
  uint4 a = *(const uint4*)(o2 + i0);
  float4 d0 = *(const float4*)(data + i0);
  float4 d1 = *(const float4*)(data + i0 + 4);
  uint ua[4] = {a.x, a.y, a.z, a.w};
  float dd[8] = {d0.x, d0.y, d0.z, d0.w, d1.x, d1.y, d1.z, d1.w};
  float y[8];
#pragma unroll
  for (int p = 0; p < 4; ++p) {
    float x0 = __uint_as_float(ua[p] << 16);
    float x1 = __uint_as_float(ua[p] & 0xffff0000u);
    y[2*p]   = leaky(sc[2*p]   * x0 + sh[2*p]   + dd[2*p]);
    y[2*p+1] = leaky(sc[2*p+1] * x1 + sh[2*p+1] + dd[2*p+1]);
  }
  float4 r0 = {y[0], y[1], y[2], y[3]};
  float4 r1 = {y[4], y[5], y[6], y[7]};
  *(float4*)(out + i0) = r0;
  *(float4*)(out + i0 + 4) = r1;
}

extern "C" void kernel_launch(void* const* d_in, const int* in_sizes, int n_in,
                              void* d_out, int out_size, void* d_ws, size_t ws_size,
                              hipStream_t stream) {
  const float* data   = (const float*)d_in[0];
  const int*   ind    = (const int*)d_in[1];
  const float* w1     = (const float*)d_in[2];
  const float* b1     = (const float*)d_in[3];
  const float* gamma1 = (const float*)d_in[4];
  const float* beta1  = (const float*)d_in[5];
  const float* w2     = (const float*)d_in[6];
  const float* gamma2 = (const float*)d_in[7];
  const float* beta2  = (const float*)d_in[8];
  float* out = (float*)d_out;

  // d_out (64MB fp32) doubles as scratch until k_final overwrites:
  //   [0,32MB)  = out1 bf16 (conv1 raw; conv2 applies BN1+leaky during gather)
  //   [32,64MB) = dataB bf16 (pre-rounded data; dead after conv1)
  ushort* out1  = (ushort*)d_out;
  ushort* dataB = out1 + (size_t)NN * CH;
  // ws: accum1[32] | accum2[32] | pad | out2 bf16 (32MB @ +4096)
  float*  accum1 = (float*)d_ws;
  float*  accum2 = accum1 + 32;
  ushort* out2   = (ushort*)((char*)d_ws + 4096);

  // cast data -> bf16 (and zero both stat accumulators in block 0)
  hipLaunchKernelGGL(k_cast, dim3((NN * CH / 8 + 255) / 256), dim3(256), 0, stream,
                     data, dataB, accum1);

  // conv1: dataB -> out1 raw + stats (2-window, barrier-free)
  hipLaunchKernelGGL((k_conv<false>), dim3(NBLK), dim3(256), 0, stream,
                     dataB, ind, w1, b1,
                     (const float*)nullptr, (const float*)nullptr, (const float*)nullptr,
                     out1, accum1);

  // conv2: gather out1, BN1+leaky in-register -> out2 raw + stats
  hipLaunchKernelGGL((k_conv<true>), dim3(NBLK), dim3(256), 0, stream,
                     out1, ind, w2, (const float*)nullptr,
                     accum1, gamma1, beta1,
                     out2, accum2);

  // residual + BN2 + leaky -> d_out (scratch regions dead)
  hipLaunchKernelGGL(k_final, dim3((NN * CH / 8 + 255) / 256), dim3(256), 0, stream,
                     out2, data, accum2, gamma2, beta2, out);
}